// Round 1
// baseline (856.676 us; speedup 1.0000x reference)
//
#include <hip/hip_runtime.h>
#include <math.h>

#define C_CLASSES 100000
#define EMBED     384
#define BATCH     512
#define S_SCALE   64.0f
#define COS_M_    0.8775825618903728f
#define SIN_M_    0.479425538604203f
#define TH_       (-0.8775825618903728f)
#define MM_       0.2397127693021015f
#define EPS_      1e-7f

#define CT   64                                  // classes per block
#define NCH  ((C_CLASSES + CT - 1) / CT)         // 1563 chunks
#define RT   256                                 // rows per tile
#define NRT  (BATCH / RT)                        // 2
#define NT   512                                 // threads per block

// ---------------------------------------------------------------------------
// Kernel A: fused normalize + GEMM chunk + margin + partial logsumexp
// grid = NCH blocks, 512 threads.
// LDS: Wq 64x96 float4 (98.3KB, XOR-swizzled) + Eq 256x9 float4 (36.9KB)
// ---------------------------------------------------------------------------
__global__ __launch_bounds__(NT, 1)
void arc_main(const float* __restrict__ emb, const int* __restrict__ labels,
              const float* __restrict__ weight,
              float* __restrict__ pmax, float* __restrict__ psum,
              float* __restrict__ zlabel)
{
    __shared__ float4 Wq[CT][96];     // 98304 B, swizzled: slot q^((c>>2)&7)
    __shared__ float4 Eq[RT][9];      // 36864 B (pad 8->9 to break banks)
    __shared__ float  partn[8][CT];
    __shared__ float  invn[CT];

    const int tid = threadIdx.x;
    const int c0  = blockIdx.x * CT;

    // ---- load W chunk (coalesced float4), swizzled store ----
    #pragma unroll
    for (int k = 0; k < 12; ++k) {
        int idx = tid + k * NT;          // 0..6143
        int c = idx / 96, q = idx % 96;
        int gc = c0 + c;
        float4 v = make_float4(0.f, 0.f, 0.f, 0.f);
        if (gc < C_CLASSES)
            v = *(const float4*)(&weight[(size_t)gc * EMBED + q * 4]);
        Wq[c][q ^ ((c >> 2) & 7)] = v;
    }
    __syncthreads();

    // ---- per-class sum of squares (8 threads per class) ----
    {
        int c = tid & 63, g = tid >> 6;     // g in 0..7
        float s = 0.f;
        #pragma unroll
        for (int k = 0; k < 12; ++k) {
            float4 v = Wq[c][(g * 12 + k) ^ ((c >> 2) & 7)];
            s += v.x * v.x + v.y * v.y + v.z * v.z + v.w * v.w;
        }
        partn[g][c] = s;
    }
    __syncthreads();
    if (tid < CT) {
        float t = 0.f;
        #pragma unroll
        for (int g = 0; g < 8; ++g) t += partn[g][tid];
        invn[tid] = (t > 0.f) ? (1.0f / sqrtf(t)) : 0.f;
    }
    __syncthreads();

    // ---- scale W rows in place (swizzle irrelevant: same row) ----
    #pragma unroll
    for (int k = 0; k < 12; ++k) {
        int idx = tid + k * NT;
        int c = idx / 96, q = idx % 96;
        float inv = invn[c];
        float4 v = Wq[c][q];
        v.x *= inv; v.y *= inv; v.z *= inv; v.w *= inv;
        Wq[c][q] = v;
    }
    __syncthreads();

    const int tx = tid & 15;     // class group: classes 4*tx .. 4*tx+3
    const int ty = tid >> 4;     // row group (0..31): rows ty + 32*i

    for (int rt = 0; rt < NRT; ++rt) {
        float acc[8][4];
        #pragma unroll
        for (int i = 0; i < 8; ++i)
            #pragma unroll
            for (int j = 0; j < 4; ++j) acc[i][j] = 0.f;

        for (int et = 0; et < 12; ++et) {      // 12 e-tiles of 32
            __syncthreads();
            // fill Eq: 256 rows x 8 float4 = 2048 / 512 threads = 4 each
            #pragma unroll
            for (int k = 0; k < 4; ++k) {
                int idx = tid + k * NT;
                int r = idx >> 3, q = idx & 7;
                Eq[r][q] = *(const float4*)(
                    &emb[((size_t)(rt * RT + r)) * EMBED + et * 32 + q * 4]);
            }
            __syncthreads();

            #pragma unroll
            for (int eq = 0; eq < 8; ++eq) {
                float4 e4[8], w4[4];
                #pragma unroll
                for (int i = 0; i < 8; ++i) e4[i] = Eq[ty + 32 * i][eq];
                int eqg = et * 8 + eq;
                #pragma unroll
                for (int j = 0; j < 4; ++j)
                    w4[j] = Wq[4 * tx + j][eqg ^ (tx & 7)];
                #pragma unroll
                for (int i = 0; i < 8; ++i)
                    #pragma unroll
                    for (int j = 0; j < 4; ++j) {
                        acc[i][j] = fmaf(e4[i].x, w4[j].x, acc[i][j]);
                        acc[i][j] = fmaf(e4[i].y, w4[j].y, acc[i][j]);
                        acc[i][j] = fmaf(e4[i].z, w4[j].z, acc[i][j]);
                        acc[i][j] = fmaf(e4[i].w, w4[j].w, acc[i][j]);
                    }
            }
        }

        // ---- epilogue: clamp, margin at label, partial logsumexp ----
        #pragma unroll
        for (int i = 0; i < 8; ++i) {
            int r   = rt * RT + ty + 32 * i;     // global row
            int lab = labels[r];
            float z[4];
            #pragma unroll
            for (int j = 0; j < 4; ++j) {
                int gc = c0 + 4 * tx + j;
                float cosv = acc[i][j];
                cosv = fminf(fmaxf(cosv, -1.f + EPS_), 1.f - EPS_);
                float zz = S_SCALE * cosv;
                if (gc == lab) {
                    float zm;
                    if (cosv > TH_) {
                        float sinv = sqrtf(fmaxf(1.f - cosv * cosv, 0.f));
                        zm = S_SCALE * (cosv * COS_M_ - sinv * SIN_M_);
                    } else {
                        zm = S_SCALE * (cosv - MM_);
                    }
                    zz = zm;
                    zlabel[r] = zm;
                }
                if (gc >= C_CLASSES) zz = -1e30f;
                z[j] = zz;
            }
            float m = fmaxf(fmaxf(z[0], z[1]), fmaxf(z[2], z[3]));
            #pragma unroll
            for (int d = 1; d < 16; d <<= 1) m = fmaxf(m, __shfl_xor(m, d, 64));
            float s = 0.f;
            #pragma unroll
            for (int j = 0; j < 4; ++j) s += expf(z[j] - m);
            #pragma unroll
            for (int d = 1; d < 16; d <<= 1) s += __shfl_xor(s, d, 64);
            if (tx == 0) {
                pmax[(size_t)r * NCH + blockIdx.x] = m;
                psum[(size_t)r * NCH + blockIdx.x] = s;
            }
        }
    }
}

// ---------------------------------------------------------------------------
// Kernel B: per-row merge of chunk partials -> row loss
// ---------------------------------------------------------------------------
__global__ __launch_bounds__(256)
void arc_reduce(const float* __restrict__ pmax, const float* __restrict__ psum,
                const float* __restrict__ zlabel, float* __restrict__ rowloss)
{
    const int r = blockIdx.x;
    const int tid = threadIdx.x;
    float m = -1e30f, s = 0.f;
    for (int k = tid; k < NCH; k += 256) {
        float m2 = pmax[(size_t)r * NCH + k];
        float s2 = psum[(size_t)r * NCH + k];
        float M = fmaxf(m, m2);
        s = s * expf(m - M) + s2 * expf(m2 - M);
        m = M;
    }
    #pragma unroll
    for (int d = 1; d < 64; d <<= 1) {
        float m2 = __shfl_xor(m, d, 64);
        float s2 = __shfl_xor(s, d, 64);
        float M = fmaxf(m, m2);
        s = s * expf(m - M) + s2 * expf(m2 - M);
        m = M;
    }
    __shared__ float sm[4], ss[4];
    if ((tid & 63) == 0) { sm[tid >> 6] = m; ss[tid >> 6] = s; }
    __syncthreads();
    if (tid == 0) {
        m = sm[0]; s = ss[0];
        #pragma unroll
        for (int w = 1; w < 4; ++w) {
            float M = fmaxf(m, sm[w]);
            s = s * expf(m - M) + ss[w] * expf(sm[w] - M);
            m = M;
        }
        rowloss[r] = (m + logf(s)) - zlabel[r];
    }
}

// ---------------------------------------------------------------------------
// Kernel C: mean over rows
// ---------------------------------------------------------------------------
__global__ __launch_bounds__(512)
void arc_mean(const float* __restrict__ rowloss, float* __restrict__ out)
{
    const int tid = threadIdx.x;
    float v = rowloss[tid];
    #pragma unroll
    for (int d = 1; d < 64; d <<= 1) v += __shfl_xor(v, d, 64);
    __shared__ float sv[8];
    if ((tid & 63) == 0) sv[tid >> 6] = v;
    __syncthreads();
    if (tid == 0) {
        float t = 0.f;
        #pragma unroll
        for (int w = 0; w < 8; ++w) t += sv[w];
        out[0] = t / (float)BATCH;
    }
}

extern "C" void kernel_launch(void* const* d_in, const int* in_sizes, int n_in,
                              void* d_out, int out_size, void* d_ws, size_t ws_size,
                              hipStream_t stream)
{
    (void)in_sizes; (void)n_in; (void)out_size; (void)ws_size;
    const float* emb    = (const float*)d_in[0];
    const int*   labels = (const int*)d_in[1];
    const float* weight = (const float*)d_in[2];
    float* out = (float*)d_out;

    float* pmax    = (float*)d_ws;                    // [BATCH][NCH]
    float* psum    = pmax + (size_t)BATCH * NCH;      // [BATCH][NCH]
    float* zlabel  = psum + (size_t)BATCH * NCH;      // [BATCH]
    float* rowloss = zlabel + BATCH;                  // [BATCH]

    arc_main<<<NCH, NT, 0, stream>>>(emb, labels, weight, pmax, psum, zlabel);
    arc_reduce<<<BATCH, 256, 0, stream>>>(pmax, psum, zlabel, rowloss);
    arc_mean<<<1, 512, 0, stream>>>(rowloss, out);
}

// Round 2
// 147.317 us; speedup vs baseline: 5.8152x; 5.8152x over previous
//
#include <hip/hip_runtime.h>
#include <hip/hip_bf16.h>
#include <math.h>

#define C_CLASSES 100000
#define EMBED     384
#define BATCH     512
#define S_SCALE   64.0f
#define COS_M_    0.8775825618903728f
#define SIN_M_    0.479425538604203f
#define TH_       (-0.8775825618903728f)
#define MM_       0.2397127693021015f
#define EPS_      1e-7f

#define CT   64
#define NCH  ((C_CLASSES + CT - 1) / CT)   // 1563
#define NT   512

typedef __attribute__((ext_vector_type(8))) short bf16x8;
typedef __attribute__((ext_vector_type(4))) float f32x4;

__device__ inline ushort f2bf(float f) {
    unsigned u = __float_as_uint(f);
    unsigned r = (u + 0x7fffu + ((u >> 16) & 1u)) >> 16;   // RNE
    return (ushort)r;
}

// ---------------------------------------------------------------------------
// Kernel 0: embeddings fp32 -> bf16 (393 KB, L2-resident afterwards)
// ---------------------------------------------------------------------------
__global__ __launch_bounds__(256)
void cvt_e(const float* __restrict__ emb, ushort* __restrict__ ebf)
{
    int i = blockIdx.x * 256 + threadIdx.x;          // float4 index
    if (i < BATCH * EMBED / 4) {
        float4 v = ((const float4*)emb)[i];
        ushort4 o;
        o.x = f2bf(v.x); o.y = f2bf(v.y); o.z = f2bf(v.z); o.w = f2bf(v.w);
        ((ushort4*)ebf)[i] = o;
    }
}

// ---------------------------------------------------------------------------
// Kernel A: fused W-normalize -> bf16 LDS -> MFMA GEMM -> margin + partial LSE
// grid = NCH blocks, 512 threads (8 waves). LDS ~51.5 KB -> 2 blocks/CU.
// ---------------------------------------------------------------------------
__global__ __launch_bounds__(NT, 4)
void arc_main(const ushort* __restrict__ ebf, const int* __restrict__ labels,
              const float* __restrict__ weight,
              float* __restrict__ pmax, float* __restrict__ psum,
              float* __restrict__ zlabel)
{
    __shared__ ushort Wl[CT * EMBED];    // 49152 B, XOR-swizzled bf16
    __shared__ float  invn[CT];
    __shared__ int    labL[BATCH];

    const int tid = threadIdx.x;
    const int blk = blockIdx.x;
    const int c0  = blk * CT;

    labL[tid] = labels[tid];

    // ---- phase A: per-class sum of squares (8 lanes per class) ----
    const int c = tid >> 3, p = tid & 7;
    const bool valid = (c0 + c) < C_CLASSES;
    const float4* wrow = (const float4*)(weight + (size_t)(c0 + c) * EMBED);
    float4 wv[12];
    float ss = 0.f;
    #pragma unroll
    for (int i = 0; i < 12; ++i) {
        float4 v = valid ? wrow[p + 8 * i] : make_float4(0.f, 0.f, 0.f, 0.f);
        wv[i] = v;
        ss += v.x * v.x + v.y * v.y + v.z * v.z + v.w * v.w;
    }
    #pragma unroll
    for (int d = 1; d < 8; d <<= 1) ss += __shfl_xor(ss, d, 64);
    if (p == 0) invn[c] = (valid && ss > 0.f) ? rsqrtf(ss) : 0.f;
    __syncthreads();

    // ---- phase B: scale + cvt bf16 + swizzled LDS store (conflict-free) ----
    {
        float inv = invn[c];
        #pragma unroll
        for (int i = 0; i < 12; ++i) {
            int q   = p + 8 * i;                 // float4 quad 0..95
            int idx = c * EMBED + q * 4;         // ushort element index
            int sw  = idx ^ ((c & 7) << 3);      // XOR bits 3..5 (16B slots)
            ushort4 o;
            o.x = f2bf(wv[i].x * inv); o.y = f2bf(wv[i].y * inv);
            o.z = f2bf(wv[i].z * inv); o.w = f2bf(wv[i].w * inv);
            *(ushort4*)&Wl[sw] = o;
        }
    }
    __syncthreads();

    // ---- phase C: MFMA GEMM, 8 waves x (4 Mtiles x 4 Ntiles), K=384 ----
    const int wid = tid >> 6, l = tid & 63;
    const int lr = l & 15, lg = l >> 4;
    const int mbase = wid * 64;

    f32x4 acc[4][4];
    #pragma unroll
    for (int mt = 0; mt < 4; ++mt)
        #pragma unroll
        for (int nt = 0; nt < 4; ++nt)
            acc[mt][nt] = (f32x4){0.f, 0.f, 0.f, 0.f};

    const ushort* eptr[4];
    #pragma unroll
    for (int mt = 0; mt < 4; ++mt)
        eptr[mt] = ebf + (size_t)(mbase + mt * 16 + lr) * EMBED + lg * 8;

    for (int ks = 0; ks < 12; ++ks) {
        bf16x8 a[4], b[4];
        #pragma unroll
        for (int mt = 0; mt < 4; ++mt)
            a[mt] = *(const bf16x8*)(eptr[mt] + ks * 32);
        #pragma unroll
        for (int nt = 0; nt < 4; ++nt) {
            int cc  = nt * 16 + lr;
            int idx = cc * EMBED + ks * 32 + lg * 8;
            b[nt] = *(const bf16x8*)&Wl[idx ^ ((cc & 7) << 3)];
        }
        #pragma unroll
        for (int mt = 0; mt < 4; ++mt)
            #pragma unroll
            for (int nt = 0; nt < 4; ++nt)
                acc[mt][nt] = __builtin_amdgcn_mfma_f32_16x16x32_bf16(
                    a[mt], b[nt], acc[mt][nt], 0, 0, 0);
    }

    // ---- epilogue: clamp, margin at label, partial logsumexp per row ----
    #pragma unroll
    for (int mt = 0; mt < 4; ++mt) {
        #pragma unroll
        for (int reg = 0; reg < 4; ++reg) {
            int r   = mbase + mt * 16 + lg * 4 + reg;
            int lab = labL[r];
            float z[4];
            #pragma unroll
            for (int nt = 0; nt < 4; ++nt) {
                int gc = c0 + nt * 16 + lr;
                float cosv = acc[mt][nt][reg];
                cosv = fminf(fmaxf(cosv, -1.f + EPS_), 1.f - EPS_);
                float zz = S_SCALE * cosv;
                if (gc == lab) {
                    float zm;
                    if (cosv > TH_) {
                        float sv = sqrtf(fmaxf(1.f - cosv * cosv, 0.f));
                        zm = S_SCALE * (cosv * COS_M_ - sv * SIN_M_);
                    } else {
                        zm = S_SCALE * (cosv - MM_);
                    }
                    zlabel[r] = zm;
                    zz = zm;
                }
                if (gc >= C_CLASSES) zz = -1e30f;
                z[nt] = zz;
            }
            float m = fmaxf(fmaxf(z[0], z[1]), fmaxf(z[2], z[3]));
            #pragma unroll
            for (int d = 1; d < 16; d <<= 1) m = fmaxf(m, __shfl_xor(m, d, 64));
            float s = 0.f;
            #pragma unroll
            for (int nt = 0; nt < 4; ++nt) s += expf(z[nt] - m);
            #pragma unroll
            for (int d = 1; d < 16; d <<= 1) s += __shfl_xor(s, d, 64);
            if (lr == 0) {
                pmax[(size_t)r * NCH + blk] = m;
                psum[(size_t)r * NCH + blk] = s;
            }
        }
    }
}

// ---------------------------------------------------------------------------
// Kernel B: per-row merge of chunk partials -> row loss
// ---------------------------------------------------------------------------
__global__ __launch_bounds__(256)
void arc_reduce(const float* __restrict__ pmax, const float* __restrict__ psum,
                const float* __restrict__ zlabel, float* __restrict__ rowloss)
{
    const int r = blockIdx.x;
    const int tid = threadIdx.x;
    float m = -1e30f, s = 0.f;
    for (int k = tid; k < NCH; k += 256) {
        float m2 = pmax[(size_t)r * NCH + k];
        float s2 = psum[(size_t)r * NCH + k];
        float M = fmaxf(m, m2);
        s = s * expf(m - M) + s2 * expf(m2 - M);
        m = M;
    }
    #pragma unroll
    for (int d = 1; d < 64; d <<= 1) {
        float m2 = __shfl_xor(m, d, 64);
        float s2 = __shfl_xor(s, d, 64);
        float M = fmaxf(m, m2);
        s = s * expf(m - M) + s2 * expf(m2 - M);
        m = M;
    }
    __shared__ float sm[4], ssh[4];
    if ((tid & 63) == 0) { sm[tid >> 6] = m; ssh[tid >> 6] = s; }
    __syncthreads();
    if (tid == 0) {
        m = sm[0]; s = ssh[0];
        #pragma unroll
        for (int w = 1; w < 4; ++w) {
            float M = fmaxf(m, sm[w]);
            s = s * expf(m - M) + ssh[w] * expf(sm[w] - M);
            m = M;
        }
        rowloss[r] = (m + logf(s)) - zlabel[r];
    }
}

// ---------------------------------------------------------------------------
// Kernel C: mean over rows
// ---------------------------------------------------------------------------
__global__ __launch_bounds__(512)
void arc_mean(const float* __restrict__ rowloss, float* __restrict__ out)
{
    const int tid = threadIdx.x;
    float v = rowloss[tid];
    #pragma unroll
    for (int d = 1; d < 64; d <<= 1) v += __shfl_xor(v, d, 64);
    __shared__ float sv[8];
    if ((tid & 63) == 0) sv[tid >> 6] = v;
    __syncthreads();
    if (tid == 0) {
        float t = 0.f;
        #pragma unroll
        for (int w = 0; w < 8; ++w) t += sv[w];
        out[0] = t / (float)BATCH;
    }
}

extern "C" void kernel_launch(void* const* d_in, const int* in_sizes, int n_in,
                              void* d_out, int out_size, void* d_ws, size_t ws_size,
                              hipStream_t stream)
{
    (void)in_sizes; (void)n_in; (void)out_size; (void)ws_size;
    const float* emb    = (const float*)d_in[0];
    const int*   labels = (const int*)d_in[1];
    const float* weight = (const float*)d_in[2];
    float* out = (float*)d_out;

    float* pmax    = (float*)d_ws;                    // [BATCH][NCH]
    float* psum    = pmax + (size_t)BATCH * NCH;      // [BATCH][NCH]
    float* zlabel  = psum + (size_t)BATCH * NCH;      // [BATCH]
    float* rowloss = zlabel + BATCH;                  // [BATCH]
    ushort* ebf    = (ushort*)(rowloss + BATCH);      // [BATCH*EMBED] bf16

    cvt_e<<<BATCH * EMBED / 4 / 256, 256, 0, stream>>>(emb, ebf);
    arc_main<<<NCH, NT, 0, stream>>>(ebf, labels, weight, pmax, psum, zlabel);
    arc_reduce<<<BATCH, 256, 0, stream>>>(pmax, psum, zlabel, rowloss);
    arc_mean<<<1, 512, 0, stream>>>(rowloss, out);
}

// Round 3
// 145.059 us; speedup vs baseline: 5.9057x; 1.0156x over previous
//
#include <hip/hip_runtime.h>
#include <hip/hip_bf16.h>
#include <math.h>

#define C_CLASSES 100000
#define EMBED     384
#define BATCH     512
#define S_SCALE   64.0f
#define COS_M_    0.8775825618903728f
#define SIN_M_    0.479425538604203f
#define TH_       (-0.8775825618903728f)
#define MM_       0.2397127693021015f
#define EPS_      1e-7f
#define LOG2E_    1.4426950408889634f
#define LN2_      0.6931471805599453f

#define CT   64
#define NCH  ((C_CLASSES + CT - 1) / CT)   // 1563
#define NT   512

typedef __attribute__((ext_vector_type(8))) short bf16x8;
typedef __attribute__((ext_vector_type(4))) float f32x4;

__device__ inline ushort f2bf(float f) {
    unsigned u = __float_as_uint(f);
    unsigned r = (u + 0x7fffu + ((u >> 16) & 1u)) >> 16;   // RNE
    return (ushort)r;
}

// ---------------------------------------------------------------------------
// Kernel 0: convert E to bf16 AND pack into MFMA A-fragment order:
//   eP[((tile*12 + ks)*64 + lane)*8 + j] = bf16(E[tile*16 + (lane&15)]
//                                               [ks*32 + (lane>>4)*8 + j])
// so the main kernel's A-load is base + lane*8 -> one coalesced 1KB wave load.
// ---------------------------------------------------------------------------
__global__ __launch_bounds__(256)
void cvt_pack_e(const float* __restrict__ emb, ushort* __restrict__ eP)
{
    int t = blockIdx.x * 256 + threadIdx.x;      // 0 .. 24575 (one 8-elem chunk)
    int lane = t & 63;
    int grp  = t >> 6;                           // tile*12 + ks
    int tile = grp / 12, ks = grp % 12;
    int lr = lane & 15, lg = lane >> 4;
    int row = tile * 16 + lr;
    int col = ks * 32 + lg * 8;
    const float4* src = (const float4*)(emb + (size_t)row * EMBED + col);
    float4 v0 = src[0], v1 = src[1];
    ushort4 o0, o1;
    o0.x = f2bf(v0.x); o0.y = f2bf(v0.y); o0.z = f2bf(v0.z); o0.w = f2bf(v0.w);
    o1.x = f2bf(v1.x); o1.y = f2bf(v1.y); o1.z = f2bf(v1.z); o1.w = f2bf(v1.w);
    ((ushort4*)eP)[t * 2]     = o0;
    ((ushort4*)eP)[t * 2 + 1] = o1;
}

// ---------------------------------------------------------------------------
// Kernel A: fused W-normalize -> bf16 LDS -> MFMA GEMM -> margin + partial LSE
// grid = NCH blocks, 512 threads (8 waves). LDS ~51 KB. ONE barrier per block.
// ---------------------------------------------------------------------------
__global__ __launch_bounds__(NT, 4)
void arc_main(const ushort* __restrict__ eP, const int* __restrict__ labels,
              const float* __restrict__ weight,
              float* __restrict__ pmax, float* __restrict__ psum,
              float* __restrict__ zlabel)
{
    __shared__ ushort Wl[CT * EMBED];    // 49152 B, XOR-swizzled bf16
    __shared__ int    labL[BATCH];

    const int tid = threadIdx.x;
    const int blk = blockIdx.x;
    const int c0  = blk * CT;

    labL[tid] = labels[tid];

    // ---- phase A: per-class sum of squares (8 lanes per class) ----
    const int c = tid >> 3, p = tid & 7;
    const bool valid = (c0 + c) < C_CLASSES;
    const float4* wrow = (const float4*)(weight + (size_t)(c0 + c) * EMBED);
    float ss = 0.f;
    #pragma unroll
    for (int i = 0; i < 12; ++i) {
        float4 v = valid ? wrow[p + 8 * i] : make_float4(0.f, 0.f, 0.f, 0.f);
        ss += v.x * v.x + v.y * v.y + v.z * v.z + v.w * v.w;
    }
    #pragma unroll
    for (int d = 1; d < 8; d <<= 1) ss += __shfl_xor(ss, d, 64);
    const float inv = (valid && ss > 0.f) ? rsqrtf(ss) : 0.f;

    // ---- phase B: scale + cvt bf16 + swizzled LDS store (reload W from L2) --
    #pragma unroll
    for (int i = 0; i < 12; ++i) {
        float4 v = valid ? wrow[p + 8 * i] : make_float4(0.f, 0.f, 0.f, 0.f);
        int q   = p + 8 * i;                 // float4 quad 0..95
        int idx = c * EMBED + q * 4;         // ushort element index
        int sw  = idx ^ ((c & 7) << 3);      // XOR bits 3..5 (16B slots)
        ushort4 o;
        o.x = f2bf(v.x * inv); o.y = f2bf(v.y * inv);
        o.z = f2bf(v.z * inv); o.w = f2bf(v.w * inv);
        *(ushort4*)&Wl[sw] = o;
    }
    __syncthreads();

    // ---- phase C: MFMA GEMM, 8 waves x (4 Mtiles x 4 Ntiles), K=384 ----
    const int wid = tid >> 6, l = tid & 63;
    const int lr = l & 15, lg = l >> 4;
    const int mbase = wid * 64;

    f32x4 acc[4][4];
    #pragma unroll
    for (int mt = 0; mt < 4; ++mt)
        #pragma unroll
        for (int nt = 0; nt < 4; ++nt)
            acc[mt][nt] = (f32x4){0.f, 0.f, 0.f, 0.f};

    // packed A base for this wave+lane: tile = wid*4 + mt
    const ushort* abase = eP + ((size_t)(wid * 4) * 12 * 64 + l) * 8;

    #pragma unroll
    for (int ks = 0; ks < 12; ++ks) {
        bf16x8 a[4], b[4];
        #pragma unroll
        for (int mt = 0; mt < 4; ++mt)
            a[mt] = *(const bf16x8*)(abase + (mt * 12 + ks) * 512);
        #pragma unroll
        for (int nt = 0; nt < 4; ++nt) {
            int cc  = nt * 16 + lr;
            int idx = cc * EMBED + ks * 32 + lg * 8;
            b[nt] = *(const bf16x8*)&Wl[idx ^ ((cc & 7) << 3)];
        }
        #pragma unroll
        for (int mt = 0; mt < 4; ++mt)
            #pragma unroll
            for (int nt = 0; nt < 4; ++nt)
                acc[mt][nt] = __builtin_amdgcn_mfma_f32_16x16x32_bf16(
                    a[mt], b[nt], acc[mt][nt], 0, 0, 0);
    }

    // ---- epilogue: clamp, margin at label, partial LSE (log2 domain) ----
    #pragma unroll
    for (int mt = 0; mt < 4; ++mt) {
        #pragma unroll
        for (int reg = 0; reg < 4; ++reg) {
            int r   = mbase + mt * 16 + lg * 4 + reg;
            int lab = labL[r];
            float z[4];
            #pragma unroll
            for (int nt = 0; nt < 4; ++nt) {
                int gc = c0 + nt * 16 + lr;
                float cosv = acc[mt][nt][reg];
                cosv = fminf(fmaxf(cosv, -1.f + EPS_), 1.f - EPS_);
                float zz = S_SCALE * cosv;
                if (gc == lab) {
                    float zm;
                    if (cosv > TH_) {
                        float sv = sqrtf(fmaxf(1.f - cosv * cosv, 0.f));
                        zm = S_SCALE * (cosv * COS_M_ - sv * SIN_M_);
                    } else {
                        zm = S_SCALE * (cosv - MM_);
                    }
                    zlabel[r] = zm;
                    zz = zm;
                }
                z[nt] = (gc >= C_CLASSES) ? -1e30f : zz * LOG2E_;
            }
            float m = fmaxf(fmaxf(z[0], z[1]), fmaxf(z[2], z[3]));
            #pragma unroll
            for (int d = 1; d < 16; d <<= 1) m = fmaxf(m, __shfl_xor(m, d, 64));
            float s = 0.f;
            #pragma unroll
            for (int nt = 0; nt < 4; ++nt) s += exp2f(z[nt] - m);
            #pragma unroll
            for (int d = 1; d < 16; d <<= 1) s += __shfl_xor(s, d, 64);
            if (lr == 0) {
                pmax[(size_t)r * NCH + blk] = m;
                psum[(size_t)r * NCH + blk] = s;
            }
        }
    }
}

// ---------------------------------------------------------------------------
// Kernel B: per-row merge of chunk partials (log2 domain) -> row loss
// ---------------------------------------------------------------------------
__global__ __launch_bounds__(256)
void arc_reduce(const float* __restrict__ pmax, const float* __restrict__ psum,
                const float* __restrict__ zlabel, float* __restrict__ rowloss)
{
    const int r = blockIdx.x;
    const int tid = threadIdx.x;
    float m = -1e30f, s = 0.f;
    for (int k = tid; k < NCH; k += 256) {
        float m2 = pmax[(size_t)r * NCH + k];
        float s2 = psum[(size_t)r * NCH + k];
        float M = fmaxf(m, m2);
        s = s * exp2f(m - M) + s2 * exp2f(m2 - M);
        m = M;
    }
    #pragma unroll
    for (int d = 1; d < 64; d <<= 1) {
        float m2 = __shfl_xor(m, d, 64);
        float s2 = __shfl_xor(s, d, 64);
        float M = fmaxf(m, m2);
        s = s * exp2f(m - M) + s2 * exp2f(m2 - M);
        m = M;
    }
    __shared__ float sm[4], ssh[4];
    if ((tid & 63) == 0) { sm[tid >> 6] = m; ssh[tid >> 6] = s; }
    __syncthreads();
    if (tid == 0) {
        m = sm[0]; s = ssh[0];
        #pragma unroll
        for (int w = 1; w < 4; ++w) {
            float M = fmaxf(m, sm[w]);
            s = s * exp2f(m - M) + ssh[w] * exp2f(sm[w] - M);
            m = M;
        }
        rowloss[r] = LN2_ * (m + log2f(s)) - zlabel[r];
    }
}

// ---------------------------------------------------------------------------
// Kernel C: mean over rows
// ---------------------------------------------------------------------------
__global__ __launch_bounds__(512)
void arc_mean(const float* __restrict__ rowloss, float* __restrict__ out)
{
    const int tid = threadIdx.x;
    float v = rowloss[tid];
    #pragma unroll
    for (int d = 1; d < 64; d <<= 1) v += __shfl_xor(v, d, 64);
    __shared__ float sv[8];
    if ((tid & 63) == 0) sv[tid >> 6] = v;
    __syncthreads();
    if (tid == 0) {
        float t = 0.f;
        #pragma unroll
        for (int w = 0; w < 8; ++w) t += sv[w];
        out[0] = t / (float)BATCH;
    }
}

extern "C" void kernel_launch(void* const* d_in, const int* in_sizes, int n_in,
                              void* d_out, int out_size, void* d_ws, size_t ws_size,
                              hipStream_t stream)
{
    (void)in_sizes; (void)n_in; (void)out_size; (void)ws_size;
    const float* emb    = (const float*)d_in[0];
    const int*   labels = (const int*)d_in[1];
    const float* weight = (const float*)d_in[2];
    float* out = (float*)d_out;

    float* pmax    = (float*)d_ws;                    // [BATCH][NCH]
    float* psum    = pmax + (size_t)BATCH * NCH;      // [BATCH][NCH]
    float* zlabel  = psum + (size_t)BATCH * NCH;      // [BATCH]
    float* rowloss = zlabel + BATCH;                  // [BATCH]
    ushort* eP     = (ushort*)(rowloss + BATCH);      // packed bf16 E fragments

    cvt_pack_e<<<(BATCH * EMBED / 8) / 256, 256, 0, stream>>>(emb, eP);
    arc_main<<<NCH, NT, 0, stream>>>(eP, labels, weight, pmax, psum, zlabel);
    arc_reduce<<<BATCH, 256, 0, stream>>>(pmax, psum, zlabel, rowloss);
    arc_mean<<<1, 512, 0, stream>>>(rowloss, out);
}